// Round 6
// baseline (194.465 us; speedup 1.0000x reference)
//
#include <hip/hip_runtime.h>
#include <hip/hip_bf16.h>

// GatingNetwork: h = x@fc_w^T + b; BatchNorm(batch axis); ReLU;
// capsule u = h @ W_caps[e]; squash; 3-iter dynamic routing; logits; softmax.
// B=131072, D_IN=HID=256, E=4, CAP=16.
//
// Pipeline: k_prep (fc_w -> bf16 hi/lo planes, [col][k], in d_out scratch);
// k_gemm (barrier-free all-register bf16x3 MFMA: A frags straight from x,
// B frags straight from L2-resident planes, BN-stats epilogue);
// k_stats; k_fuse (MFMA capsules + collinear scalar routing — verified R4).

#define BATCH   131072
#define INV_B   (1.0f / 131072.0f)

typedef __attribute__((ext_vector_type(8))) short  short8;   // 8 bf16 (4 VGPR)
typedef __attribute__((ext_vector_type(4))) float  f32x4;

// round-to-nearest-even fp32 -> bf16 (integer path; used where cost is moot)
__device__ __forceinline__ unsigned bf16_rn(float f) {
    unsigned u = __float_as_uint(f);
    return (u + 0x7fffu + ((u >> 16) & 1u)) >> 16;
}

// split 8 fp32 into bf16 hi + bf16 lo fragments (v ~= hi + lo).
// Compiler emits packed v_cvt_pk_bf16_f32; residual carried in lo.
__device__ __forceinline__ void split8s(const float* v, short8& hi, short8& lo) {
    union { ushort u16[8]; short8 v8; } ph, pl;
#pragma unroll
    for (int j = 0; j < 8; ++j) {
        union { __hip_bfloat16 b; ushort u; } ch, cl;
        ch.b = __float2bfloat16(v[j]);
        float res = v[j] - __bfloat162float(ch.b);
        cl.b = __float2bfloat16(res);
        ph.u16[j] = ch.u;
        pl.u16[j] = cl.u;
    }
    hi = ph.v8;
    lo = pl.v8;
}

__device__ __forceinline__ void split8(const float* v, uint4& hi, uint4& lo) {
    unsigned hb[8], lb[8];
#pragma unroll
    for (int j = 0; j < 8; ++j) {
        union { __hip_bfloat16 b; ushort u; } ch, cl;
        ch.b = __float2bfloat16(v[j]);
        float res = v[j] - __bfloat162float(ch.b);
        cl.b = __float2bfloat16(res);
        hb[j] = ch.u;
        lb[j] = cl.u;
    }
    hi = make_uint4(hb[0] | (hb[1] << 16), hb[2] | (hb[3] << 16),
                    hb[4] | (hb[5] << 16), hb[6] | (hb[7] << 16));
    lo = make_uint4(lb[0] | (lb[1] << 16), lb[2] | (lb[3] << 16),
                    lb[4] | (lb[5] << 16), lb[6] | (lb[7] << 16));
}

// ---------------------------------------------------------------------------
// Kernel 0: split fc_w into bf16 hi/lo planes, plain [col j][k d] layout
// (fc_w is [HID][D_IN] row-major already). hi at wsp[0..], lo at +65536.
// ---------------------------------------------------------------------------
__global__ void k_prep(const float* __restrict__ w, ushort* __restrict__ wsp)
{
    const int cid = (int)blockIdx.x * 256 + threadIdx.x;  // 0..8191 chunks of 8
    const int j = cid >> 5;
    const int d = (cid & 31) * 8;
    const float* wp = w + j * 256 + d;
    float4 v0 = *(const float4*)(wp);
    float4 v1 = *(const float4*)(wp + 4);
    float va[8] = {v0.x, v0.y, v0.z, v0.w, v1.x, v1.y, v1.z, v1.w};
    uint4 hi, lo;
    split8(va, hi, lo);
    *(uint4*)&wsp[j * 256 + d]         = hi;
    *(uint4*)&wsp[65536 + j * 256 + d] = lo;
}

// ---------------------------------------------------------------------------
// Kernel 1: barrier-free bf16x3-split MFMA GEMM
//   h[b,j] = sum_d x[b,d]*w[j,d] + bias[j]
// 256 thr = 4 waves. Block = 64 rows x 256 cols; wave wid owns cols
// wid*64..+63 (all 64 rows, acc 4x4 frags). Per (ks,kk):
//   A frag (mi): lane(g,lc) loads x[bm+mi*16+lc][ks*64+kk*32+g*8 ..+7] (32B)
//                and splits to hi/lo in-register (each x elem touched once).
//   B frag (ni): 16B loads from the L2-resident pre-split planes.
//   48 MFMA (3 products x 16). NO LDS tiles, NO barriers in the main loop.
// Epilogue: bias add, h store, per-channel sum/sumsq -> LDS -> global atomics.
// ---------------------------------------------------------------------------
__global__ __launch_bounds__(256) void k_gemm(
    const float* __restrict__ x, const ushort* __restrict__ wsp,
    const float* __restrict__ bias, float* __restrict__ h,
    float* __restrict__ gsum, float* __restrict__ gsq)
{
    __shared__ float csum[256];
    __shared__ float csq[256];

    const int t   = threadIdx.x;
    const int wn  = t >> 6;            // wave id = col slab 0..3
    const int l   = t & 63;
    const int g   = l >> 4;            // k-quarter
    const int lc  = l & 15;            // frag row/col lane
    const int bm  = (int)blockIdx.x * 64;

    csum[t] = 0.f;
    csq[t]  = 0.f;
    __syncthreads();   // init visible before epilogue atomics

    f32x4 acc[4][4];
#pragma unroll
    for (int mi = 0; mi < 4; ++mi)
#pragma unroll
        for (int ni = 0; ni < 4; ++ni)
            acc[mi][ni] = (f32x4){0.f, 0.f, 0.f, 0.f};

    float bb[4];
#pragma unroll
    for (int ni = 0; ni < 4; ++ni)
        bb[ni] = bias[wn * 64 + ni * 16 + lc];

    const ushort* wph = wsp;
    const ushort* wpl = wsp + 65536;

#pragma unroll 1
    for (int ks = 0; ks < 4; ++ks) {
#pragma unroll
        for (int kk = 0; kk < 2; ++kk) {
            const int kbase = ks * 64 + kk * 32 + g * 8;

            // B frags: 16B vector loads from L2-resident planes
            short8 bh[4], bl[4];
#pragma unroll
            for (int ni = 0; ni < 4; ++ni) {
                const int col = wn * 64 + ni * 16 + lc;
                bh[ni] = *(const short8*)&wph[col * 256 + kbase];
                bl[ni] = *(const short8*)&wpl[col * 256 + kbase];
            }

            // A frags: 32B x loads + in-register split
            short8 ah[4], al[4];
#pragma unroll
            for (int mi = 0; mi < 4; ++mi) {
                const float* ap = x + (size_t)(bm + mi * 16 + lc) * 256 + kbase;
                float4 v0 = *(const float4*)(ap);
                float4 v1 = *(const float4*)(ap + 4);
                float va[8] = {v0.x, v0.y, v0.z, v0.w, v1.x, v1.y, v1.z, v1.w};
                split8s(va, ah[mi], al[mi]);
            }

#pragma unroll
            for (int mi = 0; mi < 4; ++mi)
#pragma unroll
                for (int ni = 0; ni < 4; ++ni) {
                    acc[mi][ni] = __builtin_amdgcn_mfma_f32_16x16x32_bf16(
                        ah[mi], bh[ni], acc[mi][ni], 0, 0, 0);
                    acc[mi][ni] = __builtin_amdgcn_mfma_f32_16x16x32_bf16(
                        ah[mi], bl[ni], acc[mi][ni], 0, 0, 0);
                    acc[mi][ni] = __builtin_amdgcn_mfma_f32_16x16x32_bf16(
                        al[mi], bh[ni], acc[mi][ni], 0, 0, 0);
                }
        }
    }

    // ---- epilogue: bias add, store h, per-column stats ----
    float lsum[4] = {0.f, 0.f, 0.f, 0.f};
    float lsq[4]  = {0.f, 0.f, 0.f, 0.f};

#pragma unroll
    for (int mi = 0; mi < 4; ++mi)
#pragma unroll
        for (int ni = 0; ni < 4; ++ni) {
            const int colg = wn * 64 + ni * 16 + lc;
#pragma unroll
            for (int reg = 0; reg < 4; ++reg) {
                const int row = bm + mi * 16 + g * 4 + reg;
                float hv = acc[mi][ni][reg] + bb[ni];
                h[(size_t)row * 256 + colg] = hv;
                lsum[ni] += hv;
                lsq[ni]   = fmaf(hv, hv, lsq[ni]);
            }
        }

#pragma unroll
    for (int ni = 0; ni < 4; ++ni) {
        lsum[ni] += __shfl_xor(lsum[ni], 16);
        lsum[ni] += __shfl_xor(lsum[ni], 32);
        lsq[ni]  += __shfl_xor(lsq[ni], 16);
        lsq[ni]  += __shfl_xor(lsq[ni], 32);
    }
    if (l < 16) {
#pragma unroll
        for (int ni = 0; ni < 4; ++ni) {
            atomicAdd(&csum[wn * 64 + ni * 16 + lc], lsum[ni]);
            atomicAdd(&csq[wn * 64 + ni * 16 + lc],  lsq[ni]);
        }
    }
    __syncthreads();
    atomicAdd(&gsum[t], csum[t]);
    atomicAdd(&gsq[t],  csq[t]);
}

// ---------------------------------------------------------------------------
// Kernel 2: finalize BN stats -> per-channel scale a, shift c
// ---------------------------------------------------------------------------
__global__ void k_stats(const float* __restrict__ gsum, const float* __restrict__ gsq,
                        const float* __restrict__ gamma, const float* __restrict__ beta,
                        float* __restrict__ ab)
{
    int j = threadIdx.x;
    float mean = gsum[j] * INV_B;
    float var  = gsq[j] * INV_B - mean * mean;
    float rstd = rsqrtf(var + 1e-5f);
    float a = gamma[j] * rstd;
    ab[j]       = a;
    ab[256 + j] = beta[j] - mean * a;
}

// ---------------------------------------------------------------------------
// Kernel 3: BN+ReLU + MFMA capsule projection + collinear scalar routing.
// (unchanged from R4 — verified; ~5us warm)
// ---------------------------------------------------------------------------
__global__ __launch_bounds__(256) void k_fuse(
    const float* __restrict__ h, const float* __restrict__ ab,
    const float* __restrict__ wc, const float* __restrict__ ow_g,
    const float* __restrict__ ob_g, float* __restrict__ out)
{
    __shared__ ushort Hh[32 * 256];   // 16KB
    __shared__ ushort Hl[32 * 256];   // 16KB
    __shared__ float  us[64 * 68];    // 17KB
    __shared__ float  ows[64];

    const int t   = threadIdx.x;
    const int wid = t >> 6;
    const int l   = t & 63;
    const int g   = l >> 4;           // 0..3
    const int lc  = l & 15;

    if (t < 64) ows[t] = ow_g[t];

    // preload A-frags: A[i][k] = Wc[e=wid][d=k][o=i]
    short8 afh[8], afl[8];
#pragma unroll
    for (int ks = 0; ks < 8; ++ks) {
        union { ushort u16[8]; short8 v; } ph, pl;
#pragma unroll
        for (int j = 0; j < 8; ++j) {
            const int d = ks * 32 + g * 8 + j;
            float wv = wc[wid * 4096 + d * 16 + lc];
            unsigned hh = bf16_rn(wv);
            float res = wv - __uint_as_float(hh << 16);
            ph.u16[j] = (ushort)hh;
            pl.u16[j] = (ushort)bf16_rn(res);
        }
        afh[ks] = ph.v;
        afl[ks] = pl.v;
    }

    const int c8 = (t & 31) * 8;      // staging column group
    float a_[8], cj[8];
    {
        float4 x0 = *(const float4*)(ab + c8);
        float4 x1 = *(const float4*)(ab + c8 + 4);
        float4 y0 = *(const float4*)(ab + 256 + c8);
        float4 y1 = *(const float4*)(ab + 256 + c8 + 4);
        a_[0]=x0.x; a_[1]=x0.y; a_[2]=x0.z; a_[3]=x0.w;
        a_[4]=x1.x; a_[5]=x1.y; a_[6]=x1.z; a_[7]=x1.w;
        cj[0]=y0.x; cj[1]=y0.y; cj[2]=y0.z; cj[3]=y0.w;
        cj[4]=y1.x; cj[5]=y1.y; cj[6]=y1.z; cj[7]=y1.w;
    }

    const int rowBase = (int)blockIdx.x * 64;

#pragma unroll
    for (int sub = 0; sub < 2; ++sub) {
        const int row0 = rowBase + sub * 32;

        __syncthreads();

#pragma unroll
        for (int it = 0; it < 4; ++it) {
            const int r = it * 8 + (t >> 5);          // 0..31
            const float* hp = h + (size_t)(row0 + r) * 256 + c8;
            float4 v0 = *(const float4*)(hp);
            float4 v1 = *(const float4*)(hp + 4);
            float hv[8] = {v0.x, v0.y, v0.z, v0.w, v1.x, v1.y, v1.z, v1.w};
#pragma unroll
            for (int j = 0; j < 8; ++j)
                hv[j] = fmaxf(fmaf(hv[j], a_[j], cj[j]), 0.f);
            uint4 hi, lo;
            split8(hv, hi, lo);
            const int slot = (t & 31) ^ (r & 7);
            *(uint4*)&Hh[r * 256 + slot * 8] = hi;
            *(uint4*)&Hl[r * 256 + slot * 8] = lo;
        }
        __syncthreads();

        f32x4 acc0 = (f32x4){0.f,0.f,0.f,0.f};
        f32x4 acc1 = (f32x4){0.f,0.f,0.f,0.f};
#pragma unroll
        for (int ks = 0; ks < 8; ++ks) {
            {
                const int row  = lc;                   // nt = 0
                const int slot = (ks * 4 + g) ^ (row & 7);
                short8 bh = *(const short8*)&Hh[row * 256 + slot * 8];
                short8 bl = *(const short8*)&Hl[row * 256 + slot * 8];
                acc0 = __builtin_amdgcn_mfma_f32_16x16x32_bf16(afh[ks], bh, acc0, 0,0,0);
                acc0 = __builtin_amdgcn_mfma_f32_16x16x32_bf16(afh[ks], bl, acc0, 0,0,0);
                acc0 = __builtin_amdgcn_mfma_f32_16x16x32_bf16(afl[ks], bh, acc0, 0,0,0);
            }
            {
                const int row  = 16 + lc;              // nt = 1
                const int slot = (ks * 4 + g) ^ (row & 7);
                short8 bh = *(const short8*)&Hh[row * 256 + slot * 8];
                short8 bl = *(const short8*)&Hl[row * 256 + slot * 8];
                acc1 = __builtin_amdgcn_mfma_f32_16x16x32_bf16(afh[ks], bh, acc1, 0,0,0);
                acc1 = __builtin_amdgcn_mfma_f32_16x16x32_bf16(afh[ks], bl, acc1, 0,0,0);
                acc1 = __builtin_amdgcn_mfma_f32_16x16x32_bf16(afl[ks], bh, acc1, 0,0,0);
            }
        }
        {
            const int r0 = sub * 32 + lc;
            *(float4*)&us[r0 * 68 + wid * 16 + g * 4] =
                make_float4(acc0[0], acc0[1], acc0[2], acc0[3]);
            *(float4*)&us[(r0 + 16) * 68 + wid * 16 + g * 4] =
                make_float4(acc1[0], acc1[1], acc1[2], acc1[3]);
        }
    }
    __syncthreads();

    // routing: lane = (row_l = wid*16 + lc, e = g)
    const int row_l = wid * 16 + lc;
    float u[16];
#pragma unroll
    for (int q = 0; q < 4; ++q) {
        float4 v4 = *(const float4*)&us[row_l * 68 + g * 16 + q * 4];
        u[q*4+0] = v4.x; u[q*4+1] = v4.y; u[q*4+2] = v4.z; u[q*4+3] = v4.w;
    }

    float n2 = 0.f;
#pragma unroll
    for (int o = 0; o < 16; ++o) n2 = fmaf(u[o], u[o], n2);
    const float nrm = sqrtf(n2);
    const float sc  = nrm / ((1.f + n2) * (nrm + 1e-8f));  // u_hat = sc*u
    const float nh2 = sc * sc * n2;
    const float nh  = sc * nrm;

    float tk[4];
#pragma unroll
    for (int k = 0; k < 4; ++k) {
        float s = 0.f;
#pragma unroll
        for (int q = 0; q < 4; ++q) {
            float4 w4 = *(const float4*)&ows[k * 16 + q * 4];
            s = fmaf(u[q*4+0], w4.x, s);
            s = fmaf(u[q*4+1], w4.y, s);
            s = fmaf(u[q*4+2], w4.z, s);
            s = fmaf(u[q*4+3], w4.w, s);
        }
        tk[k] = s;
    }

    float b = 0.f, alc = 0.f;
#pragma unroll
    for (int it3 = 0; it3 < 3; ++it3) {
        float bmax = fmaxf(b, __shfl_xor(b, 16));
        bmax = fmaxf(bmax, __shfl_xor(bmax, 32));
        float eb = __expf(b - bmax);
        float es = eb + __shfl_xor(eb, 16);
        es += __shfl_xor(es, 32);
        float c = eb / es;
        float ns  = c * nh;
        float ns2 = c * c * nh2;
        float av  = ns / ((1.f + ns2) * (ns + 1e-8f));
        alc = av * c;
        if (it3 < 2) b += alc * nh2;
    }

    const float vs = alc * sc;
    float p0 = fmaf(vs, tk[0], ob_g[0]);
    float p1 = fmaf(vs, tk[1], ob_g[1]);
    float p2 = fmaf(vs, tk[2], ob_g[2]);
    float p3 = fmaf(vs, tk[3], ob_g[3]);
    float mx = fmaxf(fmaxf(p0, p1), fmaxf(p2, p3));
    float e0 = __expf(p0 - mx), e1 = __expf(p1 - mx);
    float e2 = __expf(p2 - mx), e3 = __expf(p3 - mx);
    float inv = 1.f / (e0 + e1 + e2 + e3);
    *(float4*)&out[(size_t)(rowBase + row_l) * 16 + g * 4] =
        make_float4(e0 * inv, e1 * inv, e2 * inv, e3 * inv);
}

// ---------------------------------------------------------------------------
extern "C" void kernel_launch(void* const* d_in, const int* in_sizes, int n_in,
                              void* d_out, int out_size, void* d_ws, size_t ws_size,
                              hipStream_t stream)
{
    const float* x     = (const float*)d_in[0];
    const float* fc_w  = (const float*)d_in[1];
    const float* fc_b  = (const float*)d_in[2];
    const float* gamma = (const float*)d_in[3];
    const float* beta  = (const float*)d_in[4];
    const float* wc    = (const float*)d_in[5];
    const float* ow    = (const float*)d_in[6];
    const float* ob    = (const float*)d_in[7];
    float* out = (float*)d_out;

    float* gsum = (float*)d_ws;                 // [256]
    float* gsq  = gsum + 256;                   // [256]
    float* ab   = gsum + 512;                   // [512] scale|shift
    float* h    = (float*)((char*)d_ws + 4096); // [131072*256] fp32 = 134MB

    // w-split planes live in d_out's first 256KB: written by k_prep, read by
    // k_gemm (L2-resident), then fully overwritten by k_fuse's output (8MB).
    ushort* wsp = (ushort*)d_out;               // hi[256][256] | lo[256][256]

    hipMemsetAsync(d_ws, 0, 2048, stream);      // zero gsum/gsq each call

    k_prep <<<dim3(32),   dim3(256), 0, stream>>>(fc_w, wsp);
    k_gemm <<<dim3(2048), dim3(256), 0, stream>>>(x, wsp, fc_b, h, gsum, gsq);
    k_stats<<<dim3(1),    dim3(256), 0, stream>>>(gsum, gsq, gamma, beta, ab);
    k_fuse <<<dim3(2048), dim3(256), 0, stream>>>(h, ab, wc, ow, ob, out);
}

// Round 7
// 130.183 us; speedup vs baseline: 1.4938x; 1.4938x over previous
//
#include <hip/hip_runtime.h>
#include <hip/hip_bf16.h>

// GatingNetwork: h = x@fc_w^T + b; BatchNorm(batch axis); ReLU;
// capsule u = h @ W_caps[e]; squash; 3-iter dynamic routing; logits; softmax.
// B=131072, D_IN=HID=256, E=4, CAP=16.
//
// Pipeline: k_prep (fc_w -> bf16 hi/lo planes, BK=32-step layout, slot-
// permuted for conflict-free frag reads); k_gemm (bf16x3 MFMA, BM=128 x
// BN=256, BK=32, 48KB LDS -> 2 blocks/CU, B via global_load_lds);
// k_stats; k_fuse (MFMA capsules + collinear scalar routing — verified R4).

#define BATCH   131072
#define INV_B   (1.0f / 131072.0f)

typedef __attribute__((ext_vector_type(8))) short  short8;   // 8 bf16 (4 VGPR)
typedef __attribute__((ext_vector_type(4))) float  f32x4;

// round-to-nearest-even fp32 -> bf16 (integer path; used where cost is moot)
__device__ __forceinline__ unsigned bf16_rn(float f) {
    unsigned u = __float_as_uint(f);
    return (u + 0x7fffu + ((u >> 16) & 1u)) >> 16;
}

__device__ __forceinline__ void split8(const float* v, uint4& hi, uint4& lo) {
    unsigned hb[8], lb[8];
#pragma unroll
    for (int j = 0; j < 8; ++j) {
        union { __hip_bfloat16 b; ushort u; } ch, cl;
        ch.b = __float2bfloat16(v[j]);
        float res = v[j] - __bfloat162float(ch.b);
        cl.b = __float2bfloat16(res);
        hb[j] = ch.u;
        lb[j] = cl.u;
    }
    hi = make_uint4(hb[0] | (hb[1] << 16), hb[2] | (hb[3] << 16),
                    hb[4] | (hb[5] << 16), hb[6] | (hb[7] << 16));
    lo = make_uint4(lb[0] | (lb[1] << 16), lb[2] | (lb[3] << 16),
                    lb[4] | (lb[5] << 16), lb[6] | (lb[7] << 16));
}

// ---------------------------------------------------------------------------
// Kernel 0: split fc_w into bf16 hi/lo planes grouped by BK=32 K-step, with
// the chunk permutation slot = (c + (row>>1)) & 3 pre-applied so k_gemm's
// LINEAR global_load_lds + permuted ds_read is conflict-free (2-way max).
// hi plane: wsp[ks*8192 + j*32 + slot*8], lo at +65536 (ushort units).
// ---------------------------------------------------------------------------
__global__ void k_prep(const float* __restrict__ w, ushort* __restrict__ wsp)
{
    const int cid = (int)blockIdx.x * 256 + threadIdx.x;  // 0..8191 chunks of 8
    const int j   = cid >> 5;          // output col 0..255
    const int ks  = (cid >> 2) & 7;    // K-step 0..7
    const int c   = cid & 3;           // 8-elem chunk within 32
    const float* wp = w + j * 256 + ks * 32 + c * 8;
    float4 v0 = *(const float4*)(wp);
    float4 v1 = *(const float4*)(wp + 4);
    float va[8] = {v0.x, v0.y, v0.z, v0.w, v1.x, v1.y, v1.z, v1.w};
    uint4 hi, lo;
    split8(va, hi, lo);
    const int slot = (c + (j >> 1)) & 3;
    *(uint4*)&wsp[ks * 8192 + j * 32 + slot * 8]         = hi;
    *(uint4*)&wsp[65536 + ks * 8192 + j * 32 + slot * 8] = lo;
}

// ---------------------------------------------------------------------------
// Kernel 1: bf16x3-split MFMA GEMM  h[b,j] = sum_d x[b,d]*w[j,d] + bias[j]
// BM=128, BN=256, BK=32, 512 thr = 8 waves (2M x 4N), 64x64 per wave.
// LDS 48KB + 2KB stats; __launch_bounds__(512,4) caps VGPR<=128 so
// 2 blocks/CU co-reside (16 waves/CU) — cross-block overlap hides the
// per-step barrier drains. A: coalesced load+split+permuted ds_write.
// B: global_load_lds from pre-permuted planes. acc += Ah*Bh+Ah*Bl+Al*Bh.
// ---------------------------------------------------------------------------
__global__ __launch_bounds__(512, 4) void k_gemm(
    const float* __restrict__ x, const ushort* __restrict__ wsp,
    const float* __restrict__ bias, float* __restrict__ h,
    float* __restrict__ gsum, float* __restrict__ gsq)
{
    __shared__ ushort Ah[128 * 32];   // 8KB
    __shared__ ushort Al[128 * 32];   // 8KB
    __shared__ ushort Bh[256 * 32];   // 16KB
    __shared__ ushort Bl[256 * 32];   // 16KB
    __shared__ float  csum[256];
    __shared__ float  csq[256];

    const int t   = threadIdx.x;
    const int wid = t >> 6;            // 0..7
    const int l   = t & 63;
    const int wm  = wid >> 2;          // 0..1  (64-row slab)
    const int wn  = wid & 3;           // 0..3  (64-col slab)
    const int g   = l >> 4;            // k-quarter
    const int lc  = l & 15;
    const int bm  = (int)blockIdx.x * 128;

    if (t < 256) { csum[t] = 0.f; csq[t] = 0.f; }

    f32x4 acc[4][4];
#pragma unroll
    for (int mi = 0; mi < 4; ++mi)
#pragma unroll
        for (int ni = 0; ni < 4; ++ni)
            acc[mi][ni] = (f32x4){0.f, 0.f, 0.f, 0.f};

    float bb[4];
#pragma unroll
    for (int ni = 0; ni < 4; ++ni)
        bb[ni] = bias[wn * 64 + ni * 16 + lc];

    // A-staging indices (fixed per thread): 512 chunks = 128 rows x 4 chunks
    const int ar = t >> 2;             // row 0..127
    const int ac = t & 3;              // chunk 0..3
    const int aslot = (ac + (ar >> 1)) & 3;
    const int aoff  = ar * 32 + aslot * 8;

#pragma unroll 2
    for (int ks = 0; ks < 8; ++ks) {
        const int k0 = ks * 32;
        __syncthreads();   // previous step's frag readers done

        // ---- B: async DMA of pre-permuted planes (2 rounds per plane) ----
        {
            const char* srch = (const char*)(wsp + ks * 8192);
            const char* srcl = (const char*)(wsp + 65536 + ks * 8192);
#pragma unroll
            for (int i = 0; i < 2; ++i) {
                const int off = wid * 2048 + i * 1024;   // bytes, wave-uniform
                __builtin_amdgcn_global_load_lds(
                    (const __attribute__((address_space(1))) unsigned*)(srch + off + l * 16),
                    (__attribute__((address_space(3))) unsigned*)((char*)Bh + off),
                    16, 0, 0);
                __builtin_amdgcn_global_load_lds(
                    (const __attribute__((address_space(1))) unsigned*)(srcl + off + l * 16),
                    (__attribute__((address_space(3))) unsigned*)((char*)Bl + off),
                    16, 0, 0);
            }
        }

        // ---- A: coalesced load, split, permuted store (1 chunk/thread) ----
        {
            const float* ap = x + (size_t)(bm + ar) * 256 + k0 + ac * 8;
            float4 v0 = *(const float4*)(ap);
            float4 v1 = *(const float4*)(ap + 4);
            float va[8] = {v0.x, v0.y, v0.z, v0.w, v1.x, v1.y, v1.z, v1.w};
            uint4 hi, lo;
            split8(va, hi, lo);
            *(uint4*)&Ah[aoff] = hi;
            *(uint4*)&Al[aoff] = lo;
        }
        __syncthreads();   // drains gload_lds (vmcnt) + ds_writes

        // ---- frags + 48 MFMA ----
        short8 ahf[4], alf[4], bhf[4], blf[4];
#pragma unroll
        for (int mi = 0; mi < 4; ++mi) {
            const int row  = wm * 64 + mi * 16 + lc;
            const int off  = row * 32 + (((g) + (row >> 1)) & 3) * 8;
            ahf[mi] = *(const short8*)&Ah[off];
            alf[mi] = *(const short8*)&Al[off];
        }
#pragma unroll
        for (int ni = 0; ni < 4; ++ni) {
            const int col  = wn * 64 + ni * 16 + lc;
            const int off  = col * 32 + (((g) + (col >> 1)) & 3) * 8;
            bhf[ni] = *(const short8*)&Bh[off];
            blf[ni] = *(const short8*)&Bl[off];
        }
#pragma unroll
        for (int mi = 0; mi < 4; ++mi)
#pragma unroll
            for (int ni = 0; ni < 4; ++ni) {
                acc[mi][ni] = __builtin_amdgcn_mfma_f32_16x16x32_bf16(
                    ahf[mi], bhf[ni], acc[mi][ni], 0, 0, 0);
                acc[mi][ni] = __builtin_amdgcn_mfma_f32_16x16x32_bf16(
                    ahf[mi], blf[ni], acc[mi][ni], 0, 0, 0);
                acc[mi][ni] = __builtin_amdgcn_mfma_f32_16x16x32_bf16(
                    alf[mi], bhf[ni], acc[mi][ni], 0, 0, 0);
            }
    }

    // ---- epilogue: bias add, store h, per-column stats ----
    float lsum[4] = {0.f, 0.f, 0.f, 0.f};
    float lsq[4]  = {0.f, 0.f, 0.f, 0.f};

#pragma unroll
    for (int mi = 0; mi < 4; ++mi)
#pragma unroll
        for (int ni = 0; ni < 4; ++ni) {
            const int colg = wn * 64 + ni * 16 + lc;
#pragma unroll
            for (int reg = 0; reg < 4; ++reg) {
                const int row = bm + wm * 64 + mi * 16 + g * 4 + reg;
                float hv = acc[mi][ni][reg] + bb[ni];
                h[(size_t)row * 256 + colg] = hv;
                lsum[ni] += hv;
                lsq[ni]   = fmaf(hv, hv, lsq[ni]);
            }
        }

#pragma unroll
    for (int ni = 0; ni < 4; ++ni) {
        lsum[ni] += __shfl_xor(lsum[ni], 16);
        lsum[ni] += __shfl_xor(lsum[ni], 32);
        lsq[ni]  += __shfl_xor(lsq[ni], 16);
        lsq[ni]  += __shfl_xor(lsq[ni], 32);
    }
    if (l < 16) {
#pragma unroll
        for (int ni = 0; ni < 4; ++ni) {
            atomicAdd(&csum[wn * 64 + ni * 16 + lc], lsum[ni]);
            atomicAdd(&csq[wn * 64 + ni * 16 + lc],  lsq[ni]);
        }
    }
    __syncthreads();
    if (t < 256) {
        atomicAdd(&gsum[t], csum[t]);
        atomicAdd(&gsq[t],  csq[t]);
    }
}

// ---------------------------------------------------------------------------
// Kernel 2: finalize BN stats -> per-channel scale a, shift c
// ---------------------------------------------------------------------------
__global__ void k_stats(const float* __restrict__ gsum, const float* __restrict__ gsq,
                        const float* __restrict__ gamma, const float* __restrict__ beta,
                        float* __restrict__ ab)
{
    int j = threadIdx.x;
    float mean = gsum[j] * INV_B;
    float var  = gsq[j] * INV_B - mean * mean;
    float rstd = rsqrtf(var + 1e-5f);
    float a = gamma[j] * rstd;
    ab[j]       = a;
    ab[256 + j] = beta[j] - mean * a;
}

// ---------------------------------------------------------------------------
// Kernel 3: BN+ReLU + MFMA capsule projection + collinear scalar routing.
// (unchanged from R4 — verified; ~5us warm)
// ---------------------------------------------------------------------------
__global__ __launch_bounds__(256) void k_fuse(
    const float* __restrict__ h, const float* __restrict__ ab,
    const float* __restrict__ wc, const float* __restrict__ ow_g,
    const float* __restrict__ ob_g, float* __restrict__ out)
{
    __shared__ ushort Hh[32 * 256];   // 16KB
    __shared__ ushort Hl[32 * 256];   // 16KB
    __shared__ float  us[64 * 68];    // 17KB
    __shared__ float  ows[64];

    const int t   = threadIdx.x;
    const int wid = t >> 6;
    const int l   = t & 63;
    const int g   = l >> 4;           // 0..3
    const int lc  = l & 15;

    if (t < 64) ows[t] = ow_g[t];

    // preload A-frags: A[i][k] = Wc[e=wid][d=k][o=i]
    short8 afh[8], afl[8];
#pragma unroll
    for (int ks = 0; ks < 8; ++ks) {
        union { ushort u16[8]; short8 v; } ph, pl;
#pragma unroll
        for (int j = 0; j < 8; ++j) {
            const int d = ks * 32 + g * 8 + j;
            float wv = wc[wid * 4096 + d * 16 + lc];
            unsigned hh = bf16_rn(wv);
            float res = wv - __uint_as_float(hh << 16);
            ph.u16[j] = (ushort)hh;
            pl.u16[j] = (ushort)bf16_rn(res);
        }
        afh[ks] = ph.v;
        afl[ks] = pl.v;
    }

    const int c8 = (t & 31) * 8;      // staging column group
    float a_[8], cj[8];
    {
        float4 x0 = *(const float4*)(ab + c8);
        float4 x1 = *(const float4*)(ab + c8 + 4);
        float4 y0 = *(const float4*)(ab + 256 + c8);
        float4 y1 = *(const float4*)(ab + 256 + c8 + 4);
        a_[0]=x0.x; a_[1]=x0.y; a_[2]=x0.z; a_[3]=x0.w;
        a_[4]=x1.x; a_[5]=x1.y; a_[6]=x1.z; a_[7]=x1.w;
        cj[0]=y0.x; cj[1]=y0.y; cj[2]=y0.z; cj[3]=y0.w;
        cj[4]=y1.x; cj[5]=y1.y; cj[6]=y1.z; cj[7]=y1.w;
    }

    const int rowBase = (int)blockIdx.x * 64;

#pragma unroll
    for (int sub = 0; sub < 2; ++sub) {
        const int row0 = rowBase + sub * 32;

        __syncthreads();

#pragma unroll
        for (int it = 0; it < 4; ++it) {
            const int r = it * 8 + (t >> 5);          // 0..31
            const float* hp = h + (size_t)(row0 + r) * 256 + c8;
            float4 v0 = *(const float4*)(hp);
            float4 v1 = *(const float4*)(hp + 4);
            float hv[8] = {v0.x, v0.y, v0.z, v0.w, v1.x, v1.y, v1.z, v1.w};
#pragma unroll
            for (int j = 0; j < 8; ++j)
                hv[j] = fmaxf(fmaf(hv[j], a_[j], cj[j]), 0.f);
            uint4 hi, lo;
            split8(hv, hi, lo);
            const int slot = (t & 31) ^ (r & 7);
            *(uint4*)&Hh[r * 256 + slot * 8] = hi;
            *(uint4*)&Hl[r * 256 + slot * 8] = lo;
        }
        __syncthreads();

        f32x4 acc0 = (f32x4){0.f,0.f,0.f,0.f};
        f32x4 acc1 = (f32x4){0.f,0.f,0.f,0.f};
#pragma unroll
        for (int ks = 0; ks < 8; ++ks) {
            {
                const int row  = lc;                   // nt = 0
                const int slot = (ks * 4 + g) ^ (row & 7);
                short8 bh = *(const short8*)&Hh[row * 256 + slot * 8];
                short8 bl = *(const short8*)&Hl[row * 256 + slot * 8];
                acc0 = __builtin_amdgcn_mfma_f32_16x16x32_bf16(afh[ks], bh, acc0, 0,0,0);
                acc0 = __builtin_amdgcn_mfma_f32_16x16x32_bf16(afh[ks], bl, acc0, 0,0,0);
                acc0 = __builtin_amdgcn_mfma_f32_16x16x32_bf16(afl[ks], bh, acc0, 0,0,0);
            }
            {
                const int row  = 16 + lc;              // nt = 1
                const int slot = (ks * 4 + g) ^ (row & 7);
                short8 bh = *(const short8*)&Hh[row * 256 + slot * 8];
                short8 bl = *(const short8*)&Hl[row * 256 + slot * 8];
                acc1 = __builtin_amdgcn_mfma_f32_16x16x32_bf16(afh[ks], bh, acc1, 0,0,0);
                acc1 = __builtin_amdgcn_mfma_f32_16x16x32_bf16(afh[ks], bl, acc1, 0,0,0);
                acc1 = __builtin_amdgcn_mfma_f32_16x16x32_bf16(afl[ks], bh, acc1, 0,0,0);
            }
        }
        {
            const int r0 = sub * 32 + lc;
            *(float4*)&us[r0 * 68 + wid * 16 + g * 4] =
                make_float4(acc0[0], acc0[1], acc0[2], acc0[3]);
            *(float4*)&us[(r0 + 16) * 68 + wid * 16 + g * 4] =
                make_float4(acc1[0], acc1[1], acc1[2], acc1[3]);
        }
    }
    __syncthreads();

    // routing: lane = (row_l = wid*16 + lc, e = g)
    const int row_l = wid * 16 + lc;
    float u[16];
#pragma unroll
    for (int q = 0; q < 4; ++q) {
        float4 v4 = *(const float4*)&us[row_l * 68 + g * 16 + q * 4];
        u[q*4+0] = v4.x; u[q*4+1] = v4.y; u[q*4+2] = v4.z; u[q*4+3] = v4.w;
    }

    float n2 = 0.f;
#pragma unroll
    for (int o = 0; o < 16; ++o) n2 = fmaf(u[o], u[o], n2);
    const float nrm = sqrtf(n2);
    const float sc  = nrm / ((1.f + n2) * (nrm + 1e-8f));  // u_hat = sc*u
    const float nh2 = sc * sc * n2;
    const float nh  = sc * nrm;

    float tk[4];
#pragma unroll
    for (int k = 0; k < 4; ++k) {
        float s = 0.f;
#pragma unroll
        for (int q = 0; q < 4; ++q) {
            float4 w4 = *(const float4*)&ows[k * 16 + q * 4];
            s = fmaf(u[q*4+0], w4.x, s);
            s = fmaf(u[q*4+1], w4.y, s);
            s = fmaf(u[q*4+2], w4.z, s);
            s = fmaf(u[q*4+3], w4.w, s);
        }
        tk[k] = s;
    }

    float b = 0.f, alc = 0.f;
#pragma unroll
    for (int it3 = 0; it3 < 3; ++it3) {
        float bmax = fmaxf(b, __shfl_xor(b, 16));
        bmax = fmaxf(bmax, __shfl_xor(bmax, 32));
        float eb = __expf(b - bmax);
        float es = eb + __shfl_xor(eb, 16);
        es += __shfl_xor(es, 32);
        float c = eb / es;
        float ns  = c * nh;
        float ns2 = c * c * nh2;
        float av  = ns / ((1.f + ns2) * (ns + 1e-8f));
        alc = av * c;
        if (it3 < 2) b += alc * nh2;
    }

    const float vs = alc * sc;
    float p0 = fmaf(vs, tk[0], ob_g[0]);
    float p1 = fmaf(vs, tk[1], ob_g[1]);
    float p2 = fmaf(vs, tk[2], ob_g[2]);
    float p3 = fmaf(vs, tk[3], ob_g[3]);
    float mx = fmaxf(fmaxf(p0, p1), fmaxf(p2, p3));
    float e0 = __expf(p0 - mx), e1 = __expf(p1 - mx);
    float e2 = __expf(p2 - mx), e3 = __expf(p3 - mx);
    float inv = 1.f / (e0 + e1 + e2 + e3);
    *(float4*)&out[(size_t)(rowBase + row_l) * 16 + g * 4] =
        make_float4(e0 * inv, e1 * inv, e2 * inv, e3 * inv);
}

// ---------------------------------------------------------------------------
extern "C" void kernel_launch(void* const* d_in, const int* in_sizes, int n_in,
                              void* d_out, int out_size, void* d_ws, size_t ws_size,
                              hipStream_t stream)
{
    const float* x     = (const float*)d_in[0];
    const float* fc_w  = (const float*)d_in[1];
    const float* fc_b  = (const float*)d_in[2];
    const float* gamma = (const float*)d_in[3];
    const float* beta  = (const float*)d_in[4];
    const float* wc    = (const float*)d_in[5];
    const float* ow    = (const float*)d_in[6];
    const float* ob    = (const float*)d_in[7];
    float* out = (float*)d_out;

    float* gsum = (float*)d_ws;                 // [256]
    float* gsq  = gsum + 256;                   // [256]
    float* ab   = gsum + 512;                   // [512] scale|shift
    float* h    = (float*)((char*)d_ws + 4096); // [131072*256] fp32 = 134MB

    // w-split planes live in d_out's first 256KB: written by k_prep, read by
    // k_gemm (L2-resident), then fully overwritten by k_fuse's output (8MB).
    ushort* wsp = (ushort*)d_out;               // hi|lo planes, BK=32 layout

    hipMemsetAsync(d_ws, 0, 2048, stream);      // zero gsum/gsq each call

    k_prep <<<dim3(32),   dim3(256), 0, stream>>>(fc_w, wsp);
    k_gemm <<<dim3(1024), dim3(512), 0, stream>>>(x, wsp, fc_b, h, gsum, gsq);
    k_stats<<<dim3(1),    dim3(256), 0, stream>>>(gsum, gsq, gamma, beta, ab);
    k_fuse <<<dim3(2048), dim3(256), 0, stream>>>(h, ab, wc, ow, ob, out);
}